// Round 1
// baseline (1082.707 us; speedup 1.0000x reference)
//
#include <hip/hip_runtime.h>

#define NGRAPH 100
#define NPER   1000
#define NNODES 100000
#define NEDGES 1600000
#define NB     4

// -------------------- per-layer node projections --------------------
// xproj[n,b,o] = sum_d h[n,d]*basis[l,b,d,o]
// psrc[n,o]    = sum_d h[n,d]*A_w[l,d,o]        (rows 0..31)
// pdst[n,o]    = sum_d h[n,d]*A_w[l,32+d,o]     (rows 32..63)
// nei[n,o]     = sum_d h[n,d]*self_loop_w[l,d,o]  (seed = self-loop term)
__global__ __launch_bounds__(256) void node_project_k(
    const float* __restrict__ h, const float* __restrict__ basis_l,
    const float* __restrict__ selfw_l, const float* __restrict__ Aw_l,
    float* __restrict__ xproj, float* __restrict__ psrc,
    float* __restrict__ pdst, float* __restrict__ nei)
{
    __shared__ float w_s[7168]; // [0,4096) basis, [4096,5120) selfw, [5120,6144) A1, [6144,7168) A2
    for (int k = threadIdx.x; k < 7168; k += 256) {
        float v;
        if (k < 4096)      v = basis_l[k];
        else if (k < 5120) v = selfw_l[k - 4096];
        else               v = Aw_l[k - 5120];  // A_w rows 0..63 are contiguous
        w_s[k] = v;
    }
    __syncthreads();
    int n = blockIdx.x * 256 + threadIdx.x;
    if (n >= NNODES) return;

    float hreg[32];
    const float4* hp = (const float4*)(h + (size_t)n * 32);
    #pragma unroll
    for (int k = 0; k < 8; k++) {
        float4 v = hp[k];
        hreg[4*k+0]=v.x; hreg[4*k+1]=v.y; hreg[4*k+2]=v.z; hreg[4*k+3]=v.w;
    }

    float* xout = xproj + (size_t)n * 128;
    #pragma unroll 1
    for (int b = 0; b < NB; b++) {
        const float* wb = w_s + b * 1024;
        #pragma unroll 1
        for (int o = 0; o < 32; o++) {
            float acc = 0.f;
            #pragma unroll
            for (int d = 0; d < 32; d++) acc += hreg[d] * wb[d*32 + o];
            xout[b*32 + o] = acc;
        }
    }
    #pragma unroll 1
    for (int o = 0; o < 32; o++) {
        float a0=0.f, a1=0.f, a2=0.f;
        #pragma unroll
        for (int d = 0; d < 32; d++) {
            float hd = hreg[d];
            a0 += hd * w_s[5120 + d*32 + o];
            a1 += hd * w_s[6144 + d*32 + o];
            a2 += hd * w_s[4096 + d*32 + o];
        }
        psrc[(size_t)n*32+o] = a0;
        pdst[(size_t)n*32+o] = a1;
        nei [(size_t)n*32+o] = a2;
    }
}

// -------------------- per-relation attention tables --------------------
// t1[r,o] = sum_d attn_tab[r,d]*A_w[l,64+d,o] + A_b[l,o]
// t2[r,o] = sum_d attn_tab[r,d]*A_w[l,96+d,o]
__global__ __launch_bounds__(64) void rel_tables_k(
    const float* __restrict__ attn_tab, const float* __restrict__ Aw_l,
    const float* __restrict__ Ab_l, float* __restrict__ t1, float* __restrict__ t2)
{
    int r = blockIdx.x;
    int t = threadIdx.x;
    int o = t & 31;
    bool second = t >= 32;
    const float* at = attn_tab + r * 32;
    const float* W  = Aw_l + (second ? 96*32 : 64*32);
    float acc = second ? 0.f : Ab_l[o];
    #pragma unroll
    for (int d = 0; d < 32; d++) acc += at[d] * W[d*32 + o];
    (second ? t2 : t1)[r*32 + o] = acc;
}

// -------------------- edge kernel: attention + weighted message scatter ----
__global__ __launch_bounds__(256) void edge_k(
    const int* __restrict__ src, const int* __restrict__ dst,
    const int* __restrict__ et,  const int* __restrict__ el,
    const float* __restrict__ psrc, const float* __restrict__ pdst,
    const float* __restrict__ t1,   const float* __restrict__ t2,
    const float* __restrict__ xproj, const float* __restrict__ wcomp_l,
    const float* __restrict__ Bw, const float* __restrict__ Bb,
    float* __restrict__ nei)
{
    const int lane = threadIdx.x & 63;
    const int wib  = threadIdx.x >> 6;
    const int sub  = lane >> 5;   // which of the 2 edges in this wave
    const int i    = lane & 31;   // channel
    const float bw = Bw[i];
    const float bb = Bb[0];
    long long w  = (long long)blockIdx.x * 4 + wib;
    long long nw = (long long)gridDim.x * 4;
    const long long npairs = NEDGES / 2;
    for (long long p = w; p < npairs; p += nw) {
        int e  = (int)(p * 2) + sub;
        int s_ = src[e];
        int d_ = dst[e];
        int et_ = et[e];
        int el_ = el[e];
        float z = psrc[(size_t)s_*32 + i] + pdst[(size_t)d_*32 + i]
                + t1[et_*32 + i] + t2[el_*32 + i];
        z = fmaxf(z, 0.f);
        float part = z * bw;
        part += __shfl_xor(part, 1, 32);
        part += __shfl_xor(part, 2, 32);
        part += __shfl_xor(part, 4, 32);
        part += __shfl_xor(part, 8, 32);
        part += __shfl_xor(part, 16, 32);
        float a = 1.f / (1.f + expf(-(part + bb)));
        const float* xp = xproj + (size_t)s_ * 128;
        float c0 = wcomp_l[et_*4 + 0];
        float c1 = wcomp_l[et_*4 + 1];
        float c2 = wcomp_l[et_*4 + 2];
        float c3 = wcomp_l[et_*4 + 3];
        float msg = c0*xp[i] + c1*xp[32+i] + c2*xp[64+i] + c3*xp[96+i];
        atomicAdd(&nei[(size_t)d_*32 + i], a * msg);
    }
}

// -------------------- relu + exact per-graph mean --------------------
__global__ __launch_bounds__(256) void finish_k(
    const float* __restrict__ nei, float* __restrict__ h_next,
    float* __restrict__ g_acc, int l)
{
    int g   = blockIdx.x;
    int sub = threadIdx.x >> 5;   // 0..7
    int i   = threadIdx.x & 31;
    float acc = 0.f;
    #pragma unroll 1
    for (int k = 0; k < NPER/8; k++) {
        int n = g*NPER + sub + k*8;
        float v = fmaxf(nei[(size_t)n*32 + i], 0.f);
        h_next[(size_t)n*32 + i] = v;
        acc += v;
    }
    __shared__ float red[8][32];
    red[sub][i] = acc;
    __syncthreads();
    if (threadIdx.x < 32) {
        float s2 = 0.f;
        #pragma unroll
        for (int k = 0; k < 8; k++) s2 += red[k][threadIdx.x];
        g_acc[g*96 + l*32 + threadIdx.x] = s2 * (1.0f/NPER);
    }
}

// -------------------- head/tail row gather --------------------
__global__ __launch_bounds__(256) void headtail_k(
    const float* __restrict__ h, const int* __restrict__ head_ids,
    const int* __restrict__ tail_ids, float* __restrict__ head_buf,
    float* __restrict__ tail_buf, int l)
{
    int idx = blockIdx.x * 256 + threadIdx.x;
    if (idx >= NGRAPH * 32) return;
    int g = idx >> 5;
    int i = idx & 31;
    head_buf[g*96 + l*32 + i] = h[(size_t)head_ids[g]*32 + i];
    tail_buf[g*96 + l*32 + i] = h[(size_t)tail_ids[g]*32 + i];
}

// -------------------- final readout: out[g] = g_rep . fc_w + fc_b ----------
__global__ __launch_bounds__(64) void readout_k(
    const float* __restrict__ g_acc, const float* __restrict__ head_buf,
    const float* __restrict__ tail_buf, const float* __restrict__ rel_tab,
    const int* __restrict__ rel_labels, const float* __restrict__ fc_w,
    const float* __restrict__ fc_b, float* __restrict__ out)
{
    int g = blockIdx.x;
    int t = threadIdx.x;
    float s = 0.f;
    for (int idx = t; idx < 320; idx += 64) {
        float v;
        if (idx < 96)       v = g_acc[g*96 + idx];
        else if (idx < 192) v = head_buf[g*96 + idx - 96];
        else if (idx < 288) v = tail_buf[g*96 + idx - 192];
        else                v = rel_tab[rel_labels[g]*32 + (idx - 288)];
        s += v * fc_w[idx];
    }
    s += __shfl_xor(s, 1, 64);
    s += __shfl_xor(s, 2, 64);
    s += __shfl_xor(s, 4, 64);
    s += __shfl_xor(s, 8, 64);
    s += __shfl_xor(s, 16, 64);
    s += __shfl_xor(s, 32, 64);
    if (t == 0) out[g] = s + fc_b[0];
}

extern "C" void kernel_launch(void* const* d_in, const int* in_sizes, int n_in,
                              void* d_out, int out_size, void* d_ws, size_t ws_size,
                              hipStream_t stream) {
    const float* feat        = (const float*)d_in[0];
    const float* basis       = (const float*)d_in[1];   // [3,4,32,32]
    const float* w_comp      = (const float*)d_in[2];   // [3,200,4]
    const float* self_loop_w = (const float*)d_in[3];   // [3,32,32]
    const float* A_w         = (const float*)d_in[4];   // [3,128,32]
    const float* A_b         = (const float*)d_in[5];   // [3,32]
    const float* B_w         = (const float*)d_in[6];   // [3,32,1]
    const float* B_b         = (const float*)d_in[7];   // [3,1]
    const float* attn_tab    = (const float*)d_in[8];   // [200,32]
    const float* rel_tab     = (const float*)d_in[9];   // [200,32]
    const float* fc_w        = (const float*)d_in[10];  // [320,1]
    const float* fc_b        = (const float*)d_in[11];  // [1]
    const int* src        = (const int*)d_in[12];
    const int* dst        = (const int*)d_in[13];
    const int* etype      = (const int*)d_in[14];
    const int* elabel     = (const int*)d_in[15];
    // d_in[16] = graph_ids (implicit: n / 1000)
    const int* head_ids   = (const int*)d_in[17];
    const int* tail_ids   = (const int*)d_in[18];
    const int* rel_labels = (const int*)d_in[19];

    float* ws = (float*)d_ws;
    size_t off = 0;
    float* h0    = ws + off; off += (size_t)NNODES * 32;
    float* h1    = ws + off; off += (size_t)NNODES * 32;
    float* xproj = ws + off; off += (size_t)NNODES * 128;
    float* psrc  = ws + off; off += (size_t)NNODES * 32;
    float* pdst  = ws + off; off += (size_t)NNODES * 32;
    float* nei   = ws + off; off += (size_t)NNODES * 32;
    float* t1    = ws + off; off += 200 * 32;
    float* t2    = ws + off; off += 200 * 32;
    float* g_acc    = ws + off; off += NGRAPH * 96;
    float* head_buf = ws + off; off += NGRAPH * 96;
    float* tail_buf = ws + off; off += NGRAPH * 96;

    const float* hcur = feat;
    float* hbufs[2] = { h0, h1 };
    for (int l = 0; l < 3; l++) {
        node_project_k<<<(NNODES + 255)/256, 256, 0, stream>>>(
            hcur, basis + (size_t)l*4096, self_loop_w + (size_t)l*1024,
            A_w + (size_t)l*4096, xproj, psrc, pdst, nei);
        rel_tables_k<<<200, 64, 0, stream>>>(
            attn_tab, A_w + (size_t)l*4096, A_b + (size_t)l*32, t1, t2);
        edge_k<<<2048, 256, 0, stream>>>(
            src, dst, etype, elabel, psrc, pdst, t1, t2,
            xproj, w_comp + (size_t)l*800, B_w + (size_t)l*32, B_b + l, nei);
        float* hn = hbufs[l & 1];
        finish_k<<<NGRAPH, 256, 0, stream>>>(nei, hn, g_acc, l);
        headtail_k<<<(NGRAPH*32 + 255)/256, 256, 0, stream>>>(
            hn, head_ids, tail_ids, head_buf, tail_buf, l);
        hcur = hn;
    }
    readout_k<<<NGRAPH, 64, 0, stream>>>(
        g_acc, head_buf, tail_buf, rel_tab, rel_labels, fc_w, fc_b, (float*)d_out);
}